// Round 6
// baseline (271.930 us; speedup 1.0000x reference)
//
#include <hip/hip_runtime.h>
#include <stdint.h>
#include <stddef.h>

// Sizes fixed by reference: B*T=384, N=1024, D=64, G=256. All fp32.
// K0: view -> bf16 hi/lo planes; vb[g][d] = sum_n view[g][n]*b[n][d] (exact fold)
// K1: h[bt][n][d] = sum_i x[bt][n][i]*w[n][i][d] via split-bf16 MFMA (4 terms)
//     A-frags loaded DIRECT from global (no xs staging); T-transpose in LDS;
//     raw s_barrier + lgkmcnt-only waits (no vmcnt drain -> loads/stores stream).
//     h stored split-bf16, layout hb[bt][d][n/16][hi 16n|lo 16n] (64-B runs)
// K2: out = LayerNorm(view @ h + vb) via split-bf16 MFMA (3 terms), BM=128,
//     counted vmcnt(6) + raw barriers (T4), XCD-paired bm halves.

#define LNEPS 1e-5f

typedef __attribute__((ext_vector_type(8))) short bf16x8;
typedef __attribute__((ext_vector_type(4))) float f32x4;
typedef union { unsigned u[4]; bf16x8 v; } fragu;

static __device__ __forceinline__ unsigned rne(unsigned u) {
    return u + 0x7FFFu + ((u >> 16) & 1u);
}
static __device__ __forceinline__ void split_pair(float a, float b,
                                                  unsigned& hw_, unsigned& lw_) {
    unsigned ra = rne(__float_as_uint(a));
    unsigned rb = rne(__float_as_uint(b));
    hw_ = (ra >> 16) | (rb & 0xFFFF0000u);
    float fa = a - __uint_as_float(ra & 0xFFFF0000u);
    float fb = b - __uint_as_float(rb & 0xFFFF0000u);
    unsigned sa = rne(__float_as_uint(fa));
    unsigned sb = rne(__float_as_uint(fb));
    lw_ = (sa >> 16) | (sb & 0xFFFF0000u);
}
static __device__ __forceinline__ unsigned packhl(float vv) {
    unsigned r = rne(__float_as_uint(vv));
    unsigned hif = r & 0xFFFF0000u;
    float res = vv - __uint_as_float(hif);
    unsigned s = rne(__float_as_uint(res));
    return hif | (s >> 16);
}

static __device__ __forceinline__ void gll16(const void* g, void* l) {
    __builtin_amdgcn_global_load_lds(
        (const __attribute__((address_space(1))) void*)g,
        (__attribute__((address_space(3))) void*)l, 16, 0, 0);
}

// ws layout (bytes)
#define WS_H   0u           // 384*64*1024*2*2 = 100663296
#define WS_VH  100663296u   // +524288
#define WS_VL  101187584u   // +524288
#define WS_VB  101711872u   // +65536

// ---------------------------------------------------------------- K0
__global__ __launch_bounds__(256) void k0_prep(
        const float* __restrict__ view, const float* __restrict__ bias,
        unsigned short* __restrict__ vh, unsigned short* __restrict__ vl,
        float* __restrict__ vb) {
    const int g = blockIdx.x;
    const int tid = threadIdx.x;
    float4 vv = *(const float4*)(view + g * 1024 + tid * 4);
    unsigned h01, l01, h23, l23;
    split_pair(vv.x, vv.y, h01, l01);
    split_pair(vv.z, vv.w, h23, l23);
    *(uint2*)(vh + g * 1024 + tid * 4) = make_uint2(h01, h23);
    *(uint2*)(vl + g * 1024 + tid * 4) = make_uint2(l01, l23);
    const int q = tid >> 6, d = tid & 63;
    const float* vrow = view + g * 1024;
    float a = 0.f;
    #pragma unroll 8
    for (int nn = q * 256; nn < q * 256 + 256; ++nn)
        a = fmaf(vrow[nn], bias[nn * 64 + d], a);
    __shared__ float red[4][64];
    red[q][d] = a;
    __syncthreads();
    if (tid < 64)
        vb[g * 64 + tid] = red[0][tid] + red[1][tid] + red[2][tid] + red[3][tid];
}

// ---------------------------------------------------------------- K1
// grid 256 = 64 ng(16 n) x 4 btg(96 bt); block 1024 = 16 waves, wave wv <-> n.
// Per tile (16 bt): direct-global A loads -> split -> 32 MFMA -> pack into
// T[16n][16bt][68pad] -> {lgkm barrier} -> transposed 64-B stores -> {barrier}.
__global__ __launch_bounds__(1024) void k1_node(
        const float* __restrict__ x, const float* __restrict__ w,
        unsigned char* __restrict__ hb) {
    __shared__ unsigned T[16 * 16 * 68];  // 69632 B
    const int tid = threadIdx.x;
    const int l  = tid & 63, wv = tid >> 6;
    const int lc = l & 15,  lg = l >> 4;
    const int ng = blockIdx.x & 63, btg = blockIdx.x >> 6;
    const int n0 = ng * 16, bt_base = btg * 96;
    const int n = n0 + wv;

    // ---- w fragments for this wave's n (B operand: k=i, col=d) ----
    bf16x8 bh[4][2], bl[4][2];
    #pragma unroll
    for (int cs = 0; cs < 4; ++cs) {
        #pragma unroll
        for (int kc = 0; kc < 2; ++kc) {
            const float* wp = w + (size_t)n * 4096 + (size_t)(kc * 32 + lg * 8) * 64
                                + cs * 16 + lc;
            float e[8];
            #pragma unroll
            for (int j = 0; j < 8; ++j) e[j] = wp[(size_t)j * 64];
            fragu H, L;
            #pragma unroll
            for (int k2 = 0; k2 < 4; ++k2)
                split_pair(e[2 * k2], e[2 * k2 + 1], H.u[k2], L.u[k2]);
            bh[cs][kc] = H.v;
            bl[cs][kc] = L.v;
        }
    }

    const int btl = tid >> 6;   // transpose-phase role
    const int dT  = tid & 63;

    for (int t = 0; t < 6; ++t) {
        // ---- direct global A loads: x[bt=lc][n][i = kc*32 + lg*8 ..+7] ----
        const float* xp = x + (size_t)(bt_base + t * 16 + lc) * 65536u
                            + (size_t)n * 64 + lg * 8;
        float4 x0 = *(const float4*)(xp);
        float4 x1 = *(const float4*)(xp + 4);
        float4 x2 = *(const float4*)(xp + 32);
        float4 x3 = *(const float4*)(xp + 36);

        bf16x8 ah[2], al[2];
        {
            fragu H, L;
            split_pair(x0.x, x0.y, H.u[0], L.u[0]);
            split_pair(x0.z, x0.w, H.u[1], L.u[1]);
            split_pair(x1.x, x1.y, H.u[2], L.u[2]);
            split_pair(x1.z, x1.w, H.u[3], L.u[3]);
            ah[0] = H.v; al[0] = L.v;
        }
        {
            fragu H, L;
            split_pair(x2.x, x2.y, H.u[0], L.u[0]);
            split_pair(x2.z, x2.w, H.u[1], L.u[1]);
            split_pair(x3.x, x3.y, H.u[2], L.u[2]);
            split_pair(x3.z, x3.w, H.u[3], L.u[3]);
            ah[1] = H.v; al[1] = L.v;
        }

        f32x4 acc[4];
        #pragma unroll
        for (int cs = 0; cs < 4; ++cs) acc[cs] = (f32x4){0.f, 0.f, 0.f, 0.f};
        #pragma unroll
        for (int cs = 0; cs < 4; ++cs) {
            #pragma unroll
            for (int kc = 0; kc < 2; ++kc) {
                acc[cs] = __builtin_amdgcn_mfma_f32_16x16x32_bf16(ah[kc], bh[cs][kc], acc[cs], 0, 0, 0);
                acc[cs] = __builtin_amdgcn_mfma_f32_16x16x32_bf16(ah[kc], bl[cs][kc], acc[cs], 0, 0, 0);
                acc[cs] = __builtin_amdgcn_mfma_f32_16x16x32_bf16(al[kc], bh[cs][kc], acc[cs], 0, 0, 0);
                acc[cs] = __builtin_amdgcn_mfma_f32_16x16x32_bf16(al[kc], bl[cs][kc], acc[cs], 0, 0, 0);
            }
        }
        // pack -> T[nn=wv][bt=lg*4+j][d=cs*16+lc]
        #pragma unroll
        for (int cs = 0; cs < 4; ++cs) {
            #pragma unroll
            for (int j = 0; j < 4; ++j)
                T[wv * 1088 + (lg * 4 + j) * 68 + cs * 16 + lc] = packhl(acc[cs][j]);
        }
        asm volatile("s_waitcnt lgkmcnt(0)" ::: "memory");
        __builtin_amdgcn_s_barrier();

        // ---- transpose out: thread -> (btl, dT); 64-B run [hi 16n][lo 16n] ----
        {
            unsigned vv[16];
            #pragma unroll
            for (int nn = 0; nn < 16; ++nn) vv[nn] = T[nn * 1088 + btl * 68 + dT];
            unsigned hd[8], ld[8];
            #pragma unroll
            for (int k = 0; k < 8; ++k) {
                hd[k] = (vv[2 * k] >> 16) | (vv[2 * k + 1] & 0xFFFF0000u);
                ld[k] = (vv[2 * k] & 0xFFFFu) | (vv[2 * k + 1] << 16);
            }
            unsigned char* dst = hb + (size_t)(bt_base + t * 16 + btl) * 262144u
                                    + (size_t)dT * 4096u + ng * 64;
            ((uint4*)dst)[0] = make_uint4(hd[0], hd[1], hd[2], hd[3]);
            ((uint4*)dst)[1] = make_uint4(hd[4], hd[5], hd[6], hd[7]);
            ((uint4*)dst)[2] = make_uint4(ld[0], ld[1], ld[2], ld[3]);
            ((uint4*)dst)[3] = make_uint4(ld[4], ld[5], ld[6], ld[7]);
        }
        asm volatile("s_waitcnt lgkmcnt(0)" ::: "memory");
        __builtin_amdgcn_s_barrier();
    }
}

// ---------------------------------------------------------------- K2
// grid 768; XCD-paired remap: bm=(b>>3)&1, bt=(b&7)+(b>>4)*8.
// block 256 (4 waves); BM=128, BN=64, BK=32; LDS 2*24 KB -> 3 blk/CU.
// T4 loop: stage(s+1) -> vmcnt(6) -> barrier -> ds_read+MFMA -> barrier.
#define KB2 24576

__global__ __launch_bounds__(256, 3) void k2_grid(
        const unsigned short* __restrict__ vh, const unsigned short* __restrict__ vl,
        const unsigned char* __restrict__ hb, const float* __restrict__ vb,
        const float* __restrict__ gamma, const float* __restrict__ beta,
        float* __restrict__ out) {
    __shared__ __align__(16) unsigned char smem[2 * KB2];
    const int tid = threadIdx.x;
    const int l  = tid & 63;
    const int wv = tid >> 6;
    const int b  = blockIdx.x;
    const int bm = (b >> 3) & 1;
    const int bt = (b & 7) + (b >> 4) * 8;
    const int lc = l & 15, lg = l >> 4;

    // ---- A staging (view planes): 4 calls; id=(wv*4+c)*64+l; row=id>>3 ----
    const unsigned short* a_src[4];
    int a_dst[4];
    #pragma unroll
    for (int c = 0; c < 4; ++c) {
        int id = (wv * 4 + c) * 64 + l;
        int row = id >> 3;
        int slot = id & 7;
        int sg = slot ^ (row & 7);
        int plg = sg >> 2, kcg = sg & 3;
        const unsigned short* pl = plg ? vl : vh;
        a_src[c] = pl + (size_t)(bm * 128 + row) * 1024 + kcg * 8;  // +s*32/step
        a_dst[c] = (wv * 4 + c) * 1024;
    }
    // ---- B staging (h): 2 calls; id=(wv*2+c)*64+l; d=id>>3 ----
    const unsigned char* b_src[2];
    int b_dst[2];
    #pragma unroll
    for (int c = 0; c < 2; ++c) {
        int id = (wv * 2 + c) * 64 + l;
        int d_ = id >> 3;
        int slot = id & 7;
        int sg = slot ^ (d_ & 7);
        b_src[c] = hb + (size_t)bt * 262144u + (size_t)d_ * 4096u
                      + (sg >> 2) * 64 + ((sg >> 1) & 1) * 32 + (sg & 1) * 16; // +s*128
        b_dst[c] = 16384 + (wv * 2 + c) * 1024;
    }
    // ---- fragment read offsets ----
    int aoff[2][2];
    #pragma unroll
    for (int st = 0; st < 2; ++st)
        #pragma unroll
        for (int pl = 0; pl < 2; ++pl) {
            int row = wv * 32 + st * 16 + lc;
            aoff[st][pl] = row * 128 + ((((pl << 2) | lg) ^ (row & 7)) * 16);
        }
    int boff[4][2];
    #pragma unroll
    for (int cs = 0; cs < 4; ++cs)
        #pragma unroll
        for (int pl = 0; pl < 2; ++pl) {
            int d_ = cs * 16 + lc;
            int sg = ((lg >> 1) << 2) | (pl << 1) | (lg & 1);
            boff[cs][pl] = 16384 + d_ * 128 + ((sg ^ (d_ & 7)) * 16);
        }

    f32x4 acc[2][4];
    #pragma unroll
    for (int st = 0; st < 2; ++st)
        #pragma unroll
        for (int cs = 0; cs < 4; ++cs)
            acc[st][cs] = (f32x4){0.f, 0.f, 0.f, 0.f};

#define K2_STAGE(KB, S) do {                                                  \
    _Pragma("unroll")                                                         \
    for (int c_ = 0; c_ < 4; ++c_)                                            \
        gll16(a_src[c_] + (size_t)(S) * 32, smem + (KB) + a_dst[c_]);         \
    _Pragma("unroll")                                                         \
    for (int c_ = 0; c_ < 2; ++c_)                                            \
        gll16(b_src[c_] + (size_t)(S) * 128, smem + (KB) + b_dst[c_]);        \
} while (0)

    K2_STAGE(0, 0);
    int kb = 0;
    for (int s = 0; s < 32; ++s) {
        if (s < 31) {
            K2_STAGE(kb ^ KB2, s + 1);
            asm volatile("s_waitcnt vmcnt(6)" ::: "memory");
        } else {
            asm volatile("s_waitcnt vmcnt(0)" ::: "memory");
        }
        __builtin_amdgcn_s_barrier();   // buf(s) staged for all waves
        bf16x8 a0h = *(const bf16x8*)(smem + kb + aoff[0][0]);
        bf16x8 a0l = *(const bf16x8*)(smem + kb + aoff[0][1]);
        bf16x8 a1h = *(const bf16x8*)(smem + kb + aoff[1][0]);
        bf16x8 a1l = *(const bf16x8*)(smem + kb + aoff[1][1]);
        #pragma unroll
        for (int cs = 0; cs < 4; ++cs) {
            bf16x8 bhf = *(const bf16x8*)(smem + kb + boff[cs][0]);
            bf16x8 blf = *(const bf16x8*)(smem + kb + boff[cs][1]);
            acc[0][cs] = __builtin_amdgcn_mfma_f32_16x16x32_bf16(a0h, bhf, acc[0][cs], 0, 0, 0);
            acc[0][cs] = __builtin_amdgcn_mfma_f32_16x16x32_bf16(a0h, blf, acc[0][cs], 0, 0, 0);
            acc[0][cs] = __builtin_amdgcn_mfma_f32_16x16x32_bf16(a0l, bhf, acc[0][cs], 0, 0, 0);
            acc[1][cs] = __builtin_amdgcn_mfma_f32_16x16x32_bf16(a1h, bhf, acc[1][cs], 0, 0, 0);
            acc[1][cs] = __builtin_amdgcn_mfma_f32_16x16x32_bf16(a1h, blf, acc[1][cs], 0, 0, 0);
            acc[1][cs] = __builtin_amdgcn_mfma_f32_16x16x32_bf16(a1l, bhf, acc[1][cs], 0, 0, 0);
        }
        __builtin_amdgcn_s_barrier();   // reads of buf(s) done -> reusable
        kb ^= KB2;
    }

    // ---- epilogue: +vb, LayerNorm over D=64, store ----
    float gam[4], bet[4];
    #pragma unroll
    for (int cs = 0; cs < 4; ++cs) {
        gam[cs] = gamma[cs * 16 + lc];
        bet[cs] = beta[cs * 16 + lc];
    }
    #pragma unroll
    for (int st = 0; st < 2; ++st) {
        #pragma unroll
        for (int j = 0; j < 4; ++j) {
            int g = bm * 128 + wv * 32 + st * 16 + lg * 4 + j;
            float v[4];
            float s1 = 0.f, s2 = 0.f;
            #pragma unroll
            for (int cs = 0; cs < 4; ++cs) {
                v[cs] = acc[st][cs][j] + vb[g * 64 + cs * 16 + lc];
                s1 += v[cs];
                s2 += v[cs] * v[cs];
            }
            s1 += __shfl_xor(s1, 1);  s2 += __shfl_xor(s2, 1);
            s1 += __shfl_xor(s1, 2);  s2 += __shfl_xor(s2, 2);
            s1 += __shfl_xor(s1, 4);  s2 += __shfl_xor(s2, 4);
            s1 += __shfl_xor(s1, 8);  s2 += __shfl_xor(s2, 8);
            float mu  = s1 * 0.015625f;
            float var = s2 * 0.015625f - mu * mu;
            float inv = rsqrtf(var + LNEPS);
            size_t ob = (size_t)bt * 16384u + (size_t)g * 64u;
            #pragma unroll
            for (int cs = 0; cs < 4; ++cs)
                out[ob + cs * 16 + lc] = (v[cs] - mu) * inv * gam[cs] + bet[cs];
        }
    }
#undef K2_STAGE
}

// ---------------------------------------------------------------- launch
extern "C" void kernel_launch(void* const* d_in, const int* in_sizes, int n_in,
                              void* d_out, int out_size, void* d_ws, size_t ws_size,
                              hipStream_t stream) {
    (void)in_sizes; (void)n_in; (void)out_size; (void)ws_size;
    const float* x     = (const float*)d_in[0];
    const float* view  = (const float*)d_in[1];
    const float* w     = (const float*)d_in[2];
    const float* bias  = (const float*)d_in[3];
    const float* gamma = (const float*)d_in[4];
    const float* beta  = (const float*)d_in[5];
    float* out = (float*)d_out;

    char* ws = (char*)d_ws;
    unsigned char* hb  = (unsigned char*)(ws + WS_H);
    unsigned short* vh = (unsigned short*)(ws + WS_VH);
    unsigned short* vl = (unsigned short*)(ws + WS_VL);
    float* vb          = (float*)(ws + WS_VB);

    hipLaunchKernelGGL(k0_prep, dim3(256), dim3(256), 0, stream,
                       view, bias, vh, vl, vb);
    hipLaunchKernelGGL(k1_node, dim3(256), dim3(1024), 0, stream, x, w, hb);
    hipLaunchKernelGGL(k2_grid, dim3(768), dim3(256), 0, stream,
                       vh, vl, hb, vb, gamma, beta, out);
}